// Round 7
// baseline (265.887 us; speedup 1.0000x reference)
//
#include <hip/hip_runtime.h>

#define NEG_W 8.0f
#define EPS 1e-7f
#define TPB 256
#define VPT 8                 // 8 float4 + 8 int4 per thread, one deep burst
#define BLOCKS 4096           // 4096*256*8 float4 = 8,388,608 = N/4 exactly
#define NB_L3 1664            // blocks [0,1664): normal loads (L3-resident slice,
                              // 1664*2048*32B = 104 MB < 256 MiB L3). f=0.406
                              // balances 104MB/2.7 vs 152MB/3.9 (~39us each).

typedef float f32x4 __attribute__((ext_vector_type(4)));
typedef int   i32x4 __attribute__((ext_vector_type(4)));

// Round 9. Ladder: 97us (r0 non-nt, L3-path cap 2.7 TB/s) -> 73 (r6 all-nt)
// -> 69 (r7 VPT=8, 3.9 TB/s) -> 85 REGRESS (r8 within-wave nt/normal mix:
// time ~= serial SUM of paths -> wave-level coupling + queue HOL blocking).
// Facts: write path 6.9 TB/s (fills), L2-resident read 34.5 TB/s -> the 3.9
// read cap is L2-miss service, not DRAM or CU-side; concurrency levers null
// (queues full). This round: decouple the paths at BLOCK granularity --
// each wave is pure-path. Blocks <NB_L3 read normal (slice stays L3-resident
// across iterations); blocks >=NB_L3 stream nt from HBM. If the L3 SRAM and
// HBM can serve different CUs concurrently: ~45us. Null ~66-72 => declare
// read-path roofline next round. Regress 75-85 => revert to r5.
__global__ __launch_bounds__(TPB) void bce_partial(
    const f32x4* __restrict__ out4, const i32x4* __restrict__ tgt4,
    float* __restrict__ partials) {
  const int base = blockIdx.x * (TPB * VPT) + threadIdx.x;

  f32x4 o[VPT];
  i32x4 t[VPT];
  if (blockIdx.x < NB_L3) {           // wave-uniform: pure L3-path blocks
#pragma unroll
    for (int u = 0; u < VPT; ++u) {
      const int idx = base + u * TPB;
      o[u] = out4[idx];
      t[u] = tgt4[idx];
    }
  } else {                            // pure nt/HBM-path blocks
#pragma unroll
    for (int u = 0; u < VPT; ++u) {
      const int idx = base + u * TPB;
      o[u] = __builtin_nontemporal_load(out4 + idx);
      t[u] = __builtin_nontemporal_load(tgt4 + idx);
    }
  }
  __builtin_amdgcn_sched_barrier(0);  // keep the 16-load burst clustered

  float acc0 = 0.0f, acc1 = 0.0f, acc2 = 0.0f, acc3 = 0.0f;
#pragma unroll
  for (int u = 0; u < VPT; ++u) {
    float x0 = (t[u].x == 1) ? (o[u].x + EPS) : (1.0f - o[u].x + EPS);
    float w0 = (t[u].x == 1) ? 1.0f : NEG_W;
    float x1 = (t[u].y == 1) ? (o[u].y + EPS) : (1.0f - o[u].y + EPS);
    float w1 = (t[u].y == 1) ? 1.0f : NEG_W;
    float x2 = (t[u].z == 1) ? (o[u].z + EPS) : (1.0f - o[u].z + EPS);
    float w2 = (t[u].z == 1) ? 1.0f : NEG_W;
    float x3 = (t[u].w == 1) ? (o[u].w + EPS) : (1.0f - o[u].w + EPS);
    float w3 = (t[u].w == 1) ? 1.0f : NEG_W;
    acc0 = fmaf(w0, __logf(x0), acc0);
    acc1 = fmaf(w1, __logf(x1), acc1);
    acc2 = fmaf(w2, __logf(x2), acc2);
    acc3 = fmaf(w3, __logf(x3), acc3);
  }
  float sum = -((acc0 + acc1) + (acc2 + acc3));

  // wave64 butterfly reduce
  for (int off = 32; off > 0; off >>= 1)
    sum += __shfl_down(sum, off, 64);

  __shared__ float wsum[TPB / 64];
  const int lane = threadIdx.x & 63;
  const int wid = threadIdx.x >> 6;
  if (lane == 0) wsum[wid] = sum;
  __syncthreads();
  if (threadIdx.x == 0) {
    float s = 0.0f;
    for (int w = 0; w < TPB / 64; ++w) s += wsum[w];
    partials[blockIdx.x] = s;
  }
}

// Kernel 2: single block reduces BLOCKS float partials in double, writes mean.
__global__ __launch_bounds__(TPB) void bce_finalize(
    const float* __restrict__ partials, float* __restrict__ out, int nblocks,
    double inv_n) {
  double s = 0.0;
  for (int i = threadIdx.x; i < nblocks; i += TPB) s += (double)partials[i];
  for (int off = 32; off > 0; off >>= 1)
    s += __shfl_down(s, off, 64);
  __shared__ double wsum[TPB / 64];
  const int lane = threadIdx.x & 63;
  const int wid = threadIdx.x >> 6;
  if (lane == 0) wsum[wid] = s;
  __syncthreads();
  if (threadIdx.x == 0) {
    double tot = 0.0;
    for (int w = 0; w < TPB / 64; ++w) tot += wsum[w];
    out[0] = (float)(tot * inv_n);
  }
}

extern "C" void kernel_launch(void* const* d_in, const int* in_sizes, int n_in,
                              void* d_out, int out_size, void* d_ws, size_t ws_size,
                              hipStream_t stream) {
  const f32x4* out4 = (const f32x4*)d_in[0];
  const i32x4* tgt4 = (const i32x4*)d_in[1];
  const int n = in_sizes[0];          // 33554432 = BLOCKS*TPB*VPT*4 exactly
  float* partials = (float*)d_ws;     // 4096 * 4 B = 16 KB scratch
  (void)n;

  bce_partial<<<BLOCKS, TPB, 0, stream>>>(out4, tgt4, partials);
  bce_finalize<<<1, TPB, 0, stream>>>(partials, (float*)d_out, BLOCKS,
                                      1.0 / (double)33554432);
}

// Round 8
// 250.728 us; speedup vs baseline: 1.0605x; 1.0605x over previous
//
#include <hip/hip_runtime.h>

#define NEG_W 8.0f
#define EPS 1e-7f
#define TPB 256
#define VPT 8                 // 8 float4 + 8 int4 per thread, one deep burst
#define BLOCKS 4096           // 4096*256*8 float4 = 8,388,608 = N/4 exactly

typedef float f32x4 __attribute__((ext_vector_type(4)));
typedef int   i32x4 __attribute__((ext_vector_type(4)));

// Round 10. Read-path ladder: non-nt 2.7 TB/s (L3-lookup path, backing-store-
// agnostic) -> all-nt 3.9 TB/s (r5/r7 shape, best = ~69us) -> any nt/normal
// MIX regresses to a blended rate (r8 within-wave 85us, r9 block-split 86us
// = 3.0 TB/s) => ONE shared read-service bottleneck; all-nt is optimal.
// Writes prove 6.9 TB/s one-way (harness fills) -> reads *should* have
// headroom; difference is reads are tracked by per-XCD L2 miss-handling.
// This round's discriminator: full cache bypass via inline-asm
// `global_load_dwordx4 ... sc0 sc1 nt` (system-scope non-temporal cannot be
// served/tracked by non-system-coherent L1/L2).
//   L2-MSHR-limited  -> ~45-55us (4.9-6.0 TB/s), headline ~225-235
//   fabric-return    -> null ~66-72us, declare roofline next round
__global__ __launch_bounds__(TPB) void bce_partial(
    const f32x4* __restrict__ out4, const i32x4* __restrict__ tgt4,
    float* __restrict__ partials) {
  const int base = blockIdx.x * (TPB * VPT) + threadIdx.x;

  f32x4 o[VPT];
  i32x4 t[VPT];
#pragma unroll
  for (int u = 0; u < VPT; ++u) {
    const int idx = base + u * TPB;   // coalesced within each unroll slot
    asm volatile("global_load_dwordx4 %0, %1, off sc0 sc1 nt"
                 : "=v"(o[u]) : "v"(out4 + idx));
    asm volatile("global_load_dwordx4 %0, %1, off sc0 sc1 nt"
                 : "=v"(t[u]) : "v"(tgt4 + idx));
  }
  // Single drain; "+v" on every result makes the data dependency explicit so
  // the compiler cannot hoist consumers above the wait (rule-18 hazard).
  asm volatile("s_waitcnt vmcnt(0)"
               : "+v"(o[0]), "+v"(o[1]), "+v"(o[2]), "+v"(o[3]),
                 "+v"(o[4]), "+v"(o[5]), "+v"(o[6]), "+v"(o[7]),
                 "+v"(t[0]), "+v"(t[1]), "+v"(t[2]), "+v"(t[3]),
                 "+v"(t[4]), "+v"(t[5]), "+v"(t[6]), "+v"(t[7]));
  __builtin_amdgcn_sched_barrier(0);

  float acc0 = 0.0f, acc1 = 0.0f, acc2 = 0.0f, acc3 = 0.0f;
#pragma unroll
  for (int u = 0; u < VPT; ++u) {
    float x0 = (t[u].x == 1) ? (o[u].x + EPS) : (1.0f - o[u].x + EPS);
    float w0 = (t[u].x == 1) ? 1.0f : NEG_W;
    float x1 = (t[u].y == 1) ? (o[u].y + EPS) : (1.0f - o[u].y + EPS);
    float w1 = (t[u].y == 1) ? 1.0f : NEG_W;
    float x2 = (t[u].z == 1) ? (o[u].z + EPS) : (1.0f - o[u].z + EPS);
    float w2 = (t[u].z == 1) ? 1.0f : NEG_W;
    float x3 = (t[u].w == 1) ? (o[u].w + EPS) : (1.0f - o[u].w + EPS);
    float w3 = (t[u].w == 1) ? 1.0f : NEG_W;
    acc0 = fmaf(w0, __logf(x0), acc0);
    acc1 = fmaf(w1, __logf(x1), acc1);
    acc2 = fmaf(w2, __logf(x2), acc2);
    acc3 = fmaf(w3, __logf(x3), acc3);
  }
  float sum = -((acc0 + acc1) + (acc2 + acc3));

  // wave64 butterfly reduce
  for (int off = 32; off > 0; off >>= 1)
    sum += __shfl_down(sum, off, 64);

  __shared__ float wsum[TPB / 64];
  const int lane = threadIdx.x & 63;
  const int wid = threadIdx.x >> 6;
  if (lane == 0) wsum[wid] = sum;
  __syncthreads();
  if (threadIdx.x == 0) {
    float s = 0.0f;
    for (int w = 0; w < TPB / 64; ++w) s += wsum[w];
    partials[blockIdx.x] = s;
  }
}

// Kernel 2: single block reduces BLOCKS float partials in double, writes mean.
__global__ __launch_bounds__(TPB) void bce_finalize(
    const float* __restrict__ partials, float* __restrict__ out, int nblocks,
    double inv_n) {
  double s = 0.0;
  for (int i = threadIdx.x; i < nblocks; i += TPB) s += (double)partials[i];
  for (int off = 32; off > 0; off >>= 1)
    s += __shfl_down(s, off, 64);
  __shared__ double wsum[TPB / 64];
  const int lane = threadIdx.x & 63;
  const int wid = threadIdx.x >> 6;
  if (lane == 0) wsum[wid] = s;
  __syncthreads();
  if (threadIdx.x == 0) {
    double tot = 0.0;
    for (int w = 0; w < TPB / 64; ++w) tot += wsum[w];
    out[0] = (float)(tot * inv_n);
  }
}

extern "C" void kernel_launch(void* const* d_in, const int* in_sizes, int n_in,
                              void* d_out, int out_size, void* d_ws, size_t ws_size,
                              hipStream_t stream) {
  const f32x4* out4 = (const f32x4*)d_in[0];
  const i32x4* tgt4 = (const i32x4*)d_in[1];
  const int n = in_sizes[0];          // 33554432 = BLOCKS*TPB*VPT*4 exactly
  float* partials = (float*)d_ws;     // 4096 * 4 B = 16 KB scratch
  (void)n;

  bce_partial<<<BLOCKS, TPB, 0, stream>>>(out4, tgt4, partials);
  bce_finalize<<<1, TPB, 0, stream>>>(partials, (float*)d_out, BLOCKS,
                                      1.0 / (double)33554432);
}